// Round 4
// baseline (309.691 us; speedup 1.0000x reference)
//
#include <hip/hip_runtime.h>

// ---------------------------------------------------------------------------
// SelfAttention: B=4, S=2048, D=1024, fp32 in/out, causal, no 1/sqrt(d).
// fp16 MFMA (16x16x32), fp32 accumulate, fp32 softmax.
// R4: LDS-repack epilogues (dwordx4 stores, XOR-swizzled 16KB tile aliased
// over As/Bs), vectorized softmax, fused cvt dispatch. Keeps R3's XCD-residue
// swizzles + balanced triangular decode.
//
// ws layout (MiB):
//   [0,48)    QKV fp16 slabs (Q 0-16, K 16-32, V 32-48)
//   [48,112)  S fp32 (4x2048x2048)
//   [48,64)   x_h fp16      (over S; dead before S written)
//   [64,70)   Wh  fp16 [3072,1024] (over S; dead before S written)
//   [0,32)    P fp16        (over Q,K; written after scores read them)
//   [48,64)   Vt fp16       (over S; written after softmax reads S)
// ---------------------------------------------------------------------------

typedef _Float16 h8 __attribute__((ext_vector_type(8)));
typedef float f32x4 __attribute__((ext_vector_type(4)));

#define BM 128
#define BN 128
#define BK 32

__device__ __forceinline__ void gl_lds16(const _Float16* g, _Float16* l) {
    __builtin_amdgcn_global_load_lds(
        (const __attribute__((address_space(1))) void*)g,
        (__attribute__((address_space(3))) void*)l, 16, 0, 0);
}

// NT GEMM: C[m][n] = sum_k A[m][k]*B[n][k]; A,B fp16 row-major, row stride K.
// SWZ: 1 = QKV residue (grid.x=1536), 2 = scores balanced triangle (136),
//      3 = PV residue (128). OM: 0 = fp32 C (ldc=N, +z*sCz), 2 = fp16 QKV
//      slab store (ld 1024, slab = col>>10). KLIM: clip K at m0+BM.
template<int SWZ, int OM, bool KLIM>
__global__ __launch_bounds__(256) void gemm_nt(
    const _Float16* __restrict__ A, const _Float16* __restrict__ B,
    void* __restrict__ Cp, int N, int K,
    size_t sAz, size_t sBz, size_t sCz)
{
    __shared__ __align__(16) char smem[16384];
    _Float16* As = (_Float16*)smem;            // 8 KiB [128*32] unpadded
    _Float16* Bs = (_Float16*)(smem + 8192);   // 8 KiB

    int bx, by;
    if (SWZ == 1) {
        const int r = blockIdx.x & 7, q2 = blockIdx.x >> 3;
        bx = q2 >> 3;
        by = ((q2 & 7) << 3) | r;
    } else if (SWZ == 2) {
        const int r = blockIdx.x & 7, g = blockIdx.x >> 3;   // g in 0..16
        if (g <= r) { by = r;      bx = g; }
        else        { by = 15 - r; bx = g - (r + 1); }
    } else if (SWZ == 3) {
        const int r = blockIdx.x & 7, g = blockIdx.x >> 3;   // g in 0..15
        by = (g & 1) ? (15 - r) : r;
        bx = g >> 1;
    } else {
        bx = blockIdx.x; by = blockIdx.y;
    }

    const int tid  = threadIdx.x;
    const int lane = tid & 63;
    const int wv   = tid >> 6;
    const int m0 = by * BM, n0 = bx * BN;
    const size_t z = blockIdx.z;

    // staging: wave wv stages 1KiB chunks {wv, wv+4}; lane l -> row 16c+(l>>2),
    // col halves (l&3)*8; LDS dst = c*1024B + l*16B (lane-contiguous, required).
    const int lr = lane >> 2;
    const int lc = (lane & 3) * 8;
    const _Float16* pA0 = A + z * sAz + (size_t)(m0 + wv * 16 + lr) * K + lc;
    const _Float16* pA1 = pA0 + (size_t)64 * K;
    const _Float16* pB0 = B + z * sBz + (size_t)(n0 + wv * 16 + lr) * K + lc;
    const _Float16* pB1 = pB0 + (size_t)64 * K;
    _Float16* lA0 = As + wv * 512;
    _Float16* lA1 = As + (wv + 4) * 512;
    _Float16* lB0 = Bs + wv * 512;
    _Float16* lB1 = Bs + (wv + 4) * 512;

    // MFMA geometry: 4 waves 2x2, each wave 64x64 = 4x4 frags of 16x16x32
    const int la = lane & 15;
    const int qd = lane >> 4;
    const int wm = (wv >> 1) * 64;
    const int wn = (wv & 1) * 64;

    f32x4 acc[4][4];
    #pragma unroll
    for (int i = 0; i < 4; i++)
        #pragma unroll
        for (int j = 0; j < 4; j++)
            acc[i][j] = (f32x4){0.f, 0.f, 0.f, 0.f};

    const int kEnd = KLIM ? (m0 + BM) : K;

    for (int k0 = 0; k0 < kEnd; k0 += BK) {
        gl_lds16(pA0, lA0);
        gl_lds16(pA1, lA1);
        gl_lds16(pB0, lB0);
        gl_lds16(pB1, lB1);
        pA0 += BK; pA1 += BK; pB0 += BK; pB1 += BK;
        __syncthreads();

        h8 af[4], bf[4];
        #pragma unroll
        for (int i = 0; i < 4; i++)
            af[i] = *(const h8*)&As[(wm + i * 16 + la) * BK + qd * 8];
        #pragma unroll
        for (int i = 0; i < 4; i++)
            bf[i] = *(const h8*)&Bs[(wn + i * 16 + la) * BK + qd * 8];
        #pragma unroll
        for (int i = 0; i < 4; i++)
            #pragma unroll
            for (int j = 0; j < 4; j++)
                acc[i][j] = __builtin_amdgcn_mfma_f32_16x16x32_f16(af[i], bf[j], acc[i][j], 0, 0, 0);
        __syncthreads();
    }

    // ---- LDS-repack epilogue (D frag layout: col=la, row=qd*4+rr) ----
    if (OM == 2) {
        // fp16 slab store via [128][64] half-tiles, XOR-swizzled 8-half groups
        _Float16* H = (_Float16*)smem;
        #pragma unroll
        for (int h = 0; h < 2; h++) {
            __syncthreads();
            if ((wn >> 6) == h) {
                #pragma unroll
                for (int j = 0; j < 4; j++) {
                    const int col = j * 16 + la;        // 0..63 within half
                    #pragma unroll
                    for (int i = 0; i < 4; i++)
                        #pragma unroll
                        for (int rr = 0; rr < 4; rr++) {
                            const int row = wm + i * 16 + qd * 4 + rr;
                            H[row * 64 + ((((col >> 3) ^ (row & 7)) << 3) | (col & 7))] =
                                (_Float16)acc[i][j][rr];
                        }
                }
            }
            __syncthreads();
            const int row = tid >> 1;
            const int cb  = (tid & 1) * 32;
            const int gcol = n0 + h * 64 + cb;
            _Float16* C = (_Float16*)Cp + (size_t)(gcol >> 10) * 8388608
                        + (size_t)(m0 + row) * 1024 + (gcol & 1023);
            #pragma unroll
            for (int gi = 0; gi < 4; gi++) {
                const int col = cb + gi * 8;
                h8 vv = *(const h8*)&H[row * 64 + (((col >> 3) ^ (row & 7)) << 3)];
                *(h8*)(C + gi * 8) = vv;
            }
        }
    } else {
        // fp32 store via [128][32] quarter-tiles, XOR-swizzled 4-dword groups
        float* R = (float*)smem;
        #pragma unroll
        for (int q4 = 0; q4 < 4; q4++) {
            __syncthreads();
            if ((wn >> 6) == (q4 >> 1)) {
                const int jj = (q4 & 1) * 2;
                #pragma unroll
                for (int jd = 0; jd < 2; jd++) {
                    const int col = jd * 16 + la;       // 0..31 within quarter
                    #pragma unroll
                    for (int i = 0; i < 4; i++)
                        #pragma unroll
                        for (int rr = 0; rr < 4; rr++) {
                            const int row = wm + i * 16 + qd * 4 + rr;
                            R[row * 32 + ((((col >> 2) ^ (row & 7)) << 2) | (col & 3))] =
                                acc[i][jj + jd][rr];
                        }
                }
            }
            __syncthreads();
            const int row = tid >> 1;
            const int cb  = (tid & 1) * 16;
            float* C = (float*)Cp + z * sCz + (size_t)(m0 + row) * N + n0 + q4 * 32 + cb;
            #pragma unroll
            for (int gi = 0; gi < 4; gi++) {
                const int col = cb + gi * 4;
                f32x4 vv = *(const f32x4*)&R[row * 32 + (((col >> 2) ^ (row & 7)) << 2)];
                *(f32x4*)(C + gi * 4) = vv;
            }
        }
    }
}

// fused fp32->fp16: blocks [0,4096) convert x (8M), [4096,5632) convert W (3x1M)
__global__ __launch_bounds__(256) void cvt_all(
    const float* __restrict__ x, const float* __restrict__ Wq,
    const float* __restrict__ Wk, const float* __restrict__ Wv,
    _Float16* __restrict__ x_h, _Float16* __restrict__ Wh)
{
    const int bid = blockIdx.x;
    const float* src; _Float16* dst; size_t off;
    if (bid < 4096) {
        src = x; dst = x_h; off = (size_t)bid * 2048;
    } else {
        const int b2 = bid - 4096;
        const int w = b2 >> 9;
        src = (w == 0) ? Wq : ((w == 1) ? Wk : Wv);
        dst = Wh + (size_t)w * 1048576;
        off = (size_t)(b2 & 511) * 2048;
    }
    const size_t i = off + (size_t)threadIdx.x * 8;
    float4 a = *(const float4*)(src + i);
    float4 b = *(const float4*)(src + i + 4);
    h8 o = { (_Float16)a.x, (_Float16)a.y, (_Float16)a.z, (_Float16)a.w,
             (_Float16)b.x, (_Float16)b.y, (_Float16)b.z, (_Float16)b.w };
    *(h8*)(dst + i) = o;
}

// causal row softmax: S fp32 -> P fp16. Thread t owns cols 8t..8t+7.
// Reads only k<=q; writes only k < 128-ceil(q+1) (PV's KLIM never reads more).
__global__ __launch_bounds__(256) void softmax_causal(const float* __restrict__ S,
                                                      _Float16* __restrict__ P)
{
    const int idx = blockIdx.x;          // 0..8191
    const int q = idx & 2047;
    const float* Srow = S + (size_t)idx * 2048;
    _Float16* Prow = P + (size_t)idx * 2048;
    const int t = threadIdx.x;
    const int k0 = t * 8;
    const int lane = t & 63, wv = t >> 6;
    __shared__ float red[4];

    float v[8];
    const bool any = (k0 <= q);
    if (any) {
        float4 a = *(const float4*)(Srow + k0);
        float4 b = *(const float4*)(Srow + k0 + 4);
        v[0] = a.x; v[1] = a.y; v[2] = a.z; v[3] = a.w;
        v[4] = b.x; v[5] = b.y; v[6] = b.z; v[7] = b.w;
    }
    float mx = -3.4e38f;
    #pragma unroll
    for (int j = 0; j < 8; j++)
        if (any && k0 + j <= q) mx = fmaxf(mx, v[j]);
    #pragma unroll
    for (int o = 32; o > 0; o >>= 1) mx = fmaxf(mx, __shfl_down(mx, o, 64));
    if (lane == 0) red[wv] = mx;
    __syncthreads();
    const float mall = fmaxf(fmaxf(red[0], red[1]), fmaxf(red[2], red[3]));
    __syncthreads();

    float sum = 0.f;
    #pragma unroll
    for (int j = 0; j < 8; j++) {
        float e = (any && k0 + j <= q) ? __expf(v[j] - mall) : 0.f;
        v[j] = e;
        sum += e;
    }
    #pragma unroll
    for (int o = 32; o > 0; o >>= 1) sum += __shfl_down(sum, o, 64);
    if (lane == 0) red[wv] = sum;
    __syncthreads();
    const float inv = 1.f / (red[0] + red[1] + red[2] + red[3]);

    const int kceil = ((q >> 7) + 1) << 7;       // PV reads cols < kceil
    if (k0 < kceil) {
        h8 o = { (_Float16)(v[0] * inv), (_Float16)(v[1] * inv),
                 (_Float16)(v[2] * inv), (_Float16)(v[3] * inv),
                 (_Float16)(v[4] * inv), (_Float16)(v[5] * inv),
                 (_Float16)(v[6] * inv), (_Float16)(v[7] * inv) };
        *(h8*)(Prow + k0) = o;
    }
}

// V (b,s,e) fp16 -> Vt (b,e,s) fp16, 64x64 LDS tiles
__global__ __launch_bounds__(256) void transpose_v_kernel(const _Float16* __restrict__ V,
                                                          _Float16* __restrict__ Vt)
{
    __shared__ _Float16 tile[64][72];
    const int b = blockIdx.z;
    const int s0 = blockIdx.x * 64;
    const int e0 = blockIdx.y * 64;
    const _Float16* Vb = V + (size_t)b * 2048 * 1024;
    _Float16* Vtb = Vt + (size_t)b * 1024 * 2048;
    const int r = threadIdx.x >> 2;
    const int c = (threadIdx.x & 3) * 16;

    const _Float16* src = &Vb[(size_t)(s0 + r) * 1024 + e0 + c];
    *(uint4*)&tile[r][c]     = *(const uint4*)src;
    *(uint4*)&tile[r][c + 8] = *(const uint4*)(src + 8);
    __syncthreads();

    h8 o0, o1;
    #pragma unroll
    for (int j = 0; j < 8; j++) o0[j] = tile[c + j][r];
    #pragma unroll
    for (int j = 0; j < 8; j++) o1[j] = tile[c + 8 + j][r];
    _Float16* dst = &Vtb[(size_t)(e0 + r) * 2048 + s0 + c];
    *(h8*)dst       = o0;
    *(h8*)(dst + 8) = o1;
}

extern "C" void kernel_launch(void* const* d_in, const int* in_sizes, int n_in,
                              void* d_out, int out_size, void* d_ws, size_t ws_size,
                              hipStream_t stream) {
    const float* x  = (const float*)d_in[0];
    const float* Wq = (const float*)d_in[1];
    const float* Wk = (const float*)d_in[2];
    const float* Wv = (const float*)d_in[3];
    float* out = (float*)d_out;

    const size_t MiB = 1024 * 1024;
    char* ws = (char*)d_ws;
    _Float16* QKVh = (_Float16*)ws;                     // 48 MiB (3 slabs)
    _Float16* Vh   = QKVh + (size_t)2 * 8388608;        // V slab at +32 MiB
    float*    S    = (float*)(ws + 48 * MiB);           // 64 MiB
    _Float16* x_h  = (_Float16*)(ws + 48 * MiB);        // 16 MiB (over S)
    _Float16* Wh   = (_Float16*)(ws + 64 * MiB);        // 6 MiB  (over S)
    _Float16* P    = (_Float16*)ws;                     // 32 MiB (over Q,K)
    _Float16* Vt   = (_Float16*)(ws + 48 * MiB);        // 16 MiB (over S)

    const dim3 blk(256);

    // 0) fp32 -> fp16 conversions (one dispatch)
    cvt_all<<<dim3(5632), blk, 0, stream>>>(x, Wq, Wk, Wv, x_h, Wh);

    // 1) QKV fused: M=8192, N=3072, XCD-residue swizzle, slab-store epilogue
    gemm_nt<1, 2, false><<<dim3(1536), blk, 0, stream>>>(
        x_h, Wh, QKVh, 3072, 1024, 0, 0, 0);

    // 2) scores: balanced lower-triangle decode, 136 tiles/batch, 0 idle
    gemm_nt<2, 0, false><<<dim3(136, 1, 4), blk, 0, stream>>>(
        QKVh, QKVh + 8388608, S, 2048, 1024,
        (size_t)2097152, (size_t)2097152, (size_t)4194304);

    // 3) causal softmax rows -> P fp16 (over Q,K)
    softmax_causal<<<dim3(4 * 2048), blk, 0, stream>>>(S, P);

    // 4) V -> Vt (b,e,s) (over S)
    transpose_v_kernel<<<dim3(32, 16, 4), blk, 0, stream>>>(Vh, Vt);

    // 5) out = P @ Vt^T, fp32 out, K clipped at m0+128, residue swizzle
    gemm_nt<3, 0, true><<<dim3(128, 1, 4), blk, 0, stream>>>(
        P, Vt, out, 1024, 2048,
        (size_t)4194304, (size_t)2097152, (size_t)2097152);
}

// Round 7
// 256.344 us; speedup vs baseline: 1.2081x; 1.2081x over previous
//
#include <hip/hip_runtime.h>

// ---------------------------------------------------------------------------
// SelfAttention: B=4, S=2048, D=1024, fp32 in/out, causal, no 1/sqrt(d).
// fp16 MFMA (16x16x32), fp32 accumulate, fp32 softmax.
// R7 = R6 with the global_load_lds offset bug fixed: the builtin's imm offset
// applies to BOTH global and LDS addresses (R6 used OFF=64 -> stage-1 LDS
// shifted +64B, stale fragments + OOB LDS write -> NaN). Stage-1 now folds
// +32 halves into the global pointer and always uses OFF=0.
// BK=64 two-stage K-loop (32KB LDS, half the barrier drains, 32 MFMA/drain,
// accumulation order bit-identical to BK=32). Transpose after softmax.
//
// ws layout (MiB):
//   [0,48)    QKV fp16 slabs (Q 0-16, K 16-32, V 32-48)
//   [48,112)  S fp32 (4x2048x2048)
//   [48,64)   x_h fp16      (over S; dead before S written)
//   [64,70)   Wh  fp16 [3072,1024] (over S; dead before S written)
//   [0,32)    P fp16        (over Q,K; written after scores read them)
//   [48,64)   Vt fp16       (over S; written ONLY after softmax read S)
// ---------------------------------------------------------------------------

typedef _Float16 h8 __attribute__((ext_vector_type(8)));
typedef float f32x4 __attribute__((ext_vector_type(4)));

#define BM 128
#define BN 128

__device__ __forceinline__ void gl_lds16(const _Float16* g, _Float16* l) {
    __builtin_amdgcn_global_load_lds(
        (const __attribute__((address_space(1))) void*)g,
        (__attribute__((address_space(3))) void*)l, 16, 0, 0);
}

// NT GEMM: C[m][n] = sum_k A[m][k]*B[n][k]; A,B fp16 row-major, stride K.
// SWZ: 1 = QKV residue (grid.x=1536), 2 = scores balanced triangle (136),
//      3 = PV residue (128). OM: 0 = fp32 C (ldc=N, +z*sCz), 2 = fp16 QKV
//      slab store. KLIM: clip K at m0+BM.
template<int SWZ, int OM, bool KLIM>
__global__ __launch_bounds__(256) void gemm_nt(
    const _Float16* __restrict__ A, const _Float16* __restrict__ B,
    void* __restrict__ Cp, int N, int K,
    size_t sAz, size_t sBz, size_t sCz)
{
    __shared__ __align__(16) char smem[32768];
    _Float16* As = (_Float16*)smem;              // 2 x 4096 halves (k-stages)
    _Float16* Bs = (_Float16*)(smem + 16384);    // 2 x 4096 halves

    int bx, by;
    if (SWZ == 1) {
        const int r = blockIdx.x & 7, q2 = blockIdx.x >> 3;
        bx = q2 >> 3;
        by = ((q2 & 7) << 3) | r;
    } else if (SWZ == 2) {
        const int r = blockIdx.x & 7, g = blockIdx.x >> 3;   // g in 0..16
        if (g <= r) { by = r;      bx = g; }
        else        { by = 15 - r; bx = g - (r + 1); }
    } else {                                      // SWZ == 3
        const int r = blockIdx.x & 7, g = blockIdx.x >> 3;   // g in 0..15
        by = (g & 1) ? (15 - r) : r;
        bx = g >> 1;
    }

    const int tid  = threadIdx.x;
    const int lane = tid & 63;
    const int wv   = tid >> 6;
    const int m0 = by * BM, n0 = bx * BN;
    const size_t z = blockIdx.z;

    // staging (per 8KB stage): 8 chunks of 1KB; wave wv stages chunks {wv,wv+4};
    // lane l -> row 16c+(l>>2), col halves (l&3)*8; stage 1 = +32 halves in
    // GLOBAL pointer (imm offset would shift the LDS address too!).
    // LDS dst = stage*8KB + c*1KB + l*16B (lane-contiguous, required).
    const int lr = lane >> 2;
    const int lc = (lane & 3) * 8;
    const _Float16* pA0 = A + z * sAz + (size_t)(m0 + wv * 16 + lr) * K + lc;
    const _Float16* pA1 = pA0 + (size_t)64 * K;
    const _Float16* pB0 = B + z * sBz + (size_t)(n0 + wv * 16 + lr) * K + lc;
    const _Float16* pB1 = pB0 + (size_t)64 * K;
    _Float16* lA0 = As + wv * 512;
    _Float16* lA1 = As + (wv + 4) * 512;
    _Float16* lB0 = Bs + wv * 512;
    _Float16* lB1 = Bs + (wv + 4) * 512;

    // MFMA geometry: 4 waves 2x2, each wave 64x64 = 4x4 frags of 16x16x32
    const int la = lane & 15;
    const int qd = lane >> 4;
    const int wm = (wv >> 1) * 64;
    const int wn = (wv & 1) * 64;

    f32x4 acc[4][4];
    #pragma unroll
    for (int i = 0; i < 4; i++)
        #pragma unroll
        for (int j = 0; j < 4; j++)
            acc[i][j] = (f32x4){0.f, 0.f, 0.f, 0.f};

    const int kEnd = KLIM ? (m0 + BM) : K;

    for (int k0 = 0; k0 < kEnd; k0 += 64) {
        gl_lds16(pA0,      lA0);
        gl_lds16(pA1,      lA1);
        gl_lds16(pB0,      lB0);
        gl_lds16(pB1,      lB1);
        gl_lds16(pA0 + 32, lA0 + 4096);
        gl_lds16(pA1 + 32, lA1 + 4096);
        gl_lds16(pB0 + 32, lB0 + 4096);
        gl_lds16(pB1 + 32, lB1 + 4096);
        pA0 += 64; pA1 += 64; pB0 += 64; pB1 += 64;
        __syncthreads();

        #pragma unroll
        for (int s = 0; s < 2; s++) {
            h8 af[4], bf[4];
            #pragma unroll
            for (int i = 0; i < 4; i++)
                af[i] = *(const h8*)&As[s * 4096 + (wm + i * 16 + la) * 32 + qd * 8];
            #pragma unroll
            for (int i = 0; i < 4; i++)
                bf[i] = *(const h8*)&Bs[s * 4096 + (wn + i * 16 + la) * 32 + qd * 8];
            #pragma unroll
            for (int i = 0; i < 4; i++)
                #pragma unroll
                for (int j = 0; j < 4; j++)
                    acc[i][j] = __builtin_amdgcn_mfma_f32_16x16x32_f16(af[i], bf[j], acc[i][j], 0, 0, 0);
        }
        __syncthreads();
    }

    // epilogue (direct stores): D layout col=lane&15, row=qd*4+reg
    if (OM == 2) {
        // slab store: col 0..3071 -> slab col>>10, within-slab ld 1024
        _Float16* C = (_Float16*)Cp;
        #pragma unroll
        for (int i = 0; i < 4; i++)
            #pragma unroll
            for (int j = 0; j < 4; j++) {
                const int col  = n0 + wn + j * 16 + la;
                const size_t base = (size_t)(col >> 10) * 8388608 + (col & 1023);
                #pragma unroll
                for (int rr = 0; rr < 4; rr++)
                    C[base + (size_t)(m0 + wm + i * 16 + qd * 4 + rr) * 1024] =
                        (_Float16)acc[i][j][rr];
            }
    } else {
        float* C = (float*)Cp + z * sCz;
        #pragma unroll
        for (int i = 0; i < 4; i++)
            #pragma unroll
            for (int j = 0; j < 4; j++)
                #pragma unroll
                for (int rr = 0; rr < 4; rr++)
                    C[(size_t)(m0 + wm + i * 16 + qd * 4 + rr) * N + (n0 + wn + j * 16 + la)] =
                        acc[i][j][rr];
    }
}

// fused fp32->fp16: blocks [0,4096) convert x (8M), [4096,5632) convert W (3x1M)
__global__ __launch_bounds__(256) void cvt_all(
    const float* __restrict__ x, const float* __restrict__ Wq,
    const float* __restrict__ Wk, const float* __restrict__ Wv,
    _Float16* __restrict__ x_h, _Float16* __restrict__ Wh)
{
    const int bid = blockIdx.x;
    const float* src; _Float16* dst; size_t off;
    if (bid < 4096) {
        src = x; dst = x_h; off = (size_t)bid * 2048;
    } else {
        const int b2 = bid - 4096;
        const int w = b2 >> 9;
        src = (w == 0) ? Wq : ((w == 1) ? Wk : Wv);
        dst = Wh + (size_t)w * 1048576;
        off = (size_t)(b2 & 511) * 2048;
    }
    const size_t i = off + (size_t)threadIdx.x * 8;
    float4 a = *(const float4*)(src + i);
    float4 b = *(const float4*)(src + i + 4);
    h8 o = { (_Float16)a.x, (_Float16)a.y, (_Float16)a.z, (_Float16)a.w,
             (_Float16)b.x, (_Float16)b.y, (_Float16)b.z, (_Float16)b.w };
    *(h8*)(dst + i) = o;
}

// causal row softmax: S fp32 -> P fp16. Thread t owns cols 8t..8t+7.
// Reads only k<=q; writes only k < 128-ceil(q+1) (PV's KLIM never reads more).
__global__ __launch_bounds__(256) void softmax_causal(const float* __restrict__ S,
                                                      _Float16* __restrict__ P)
{
    const int idx = blockIdx.x;          // 0..8191
    const int q = idx & 2047;
    const float* Srow = S + (size_t)idx * 2048;
    _Float16* Prow = P + (size_t)idx * 2048;
    const int t = threadIdx.x;
    const int k0 = t * 8;
    const int lane = t & 63, wv = t >> 6;
    __shared__ float red[4];

    float v[8];
    const bool any = (k0 <= q);
    if (any) {
        float4 a = *(const float4*)(Srow + k0);
        float4 b = *(const float4*)(Srow + k0 + 4);
        v[0] = a.x; v[1] = a.y; v[2] = a.z; v[3] = a.w;
        v[4] = b.x; v[5] = b.y; v[6] = b.z; v[7] = b.w;
    }
    float mx = -3.4e38f;
    #pragma unroll
    for (int j = 0; j < 8; j++)
        if (any && k0 + j <= q) mx = fmaxf(mx, v[j]);
    #pragma unroll
    for (int o = 32; o > 0; o >>= 1) mx = fmaxf(mx, __shfl_down(mx, o, 64));
    if (lane == 0) red[wv] = mx;
    __syncthreads();
    const float mall = fmaxf(fmaxf(red[0], red[1]), fmaxf(red[2], red[3]));
    __syncthreads();

    float sum = 0.f;
    #pragma unroll
    for (int j = 0; j < 8; j++) {
        float e = (any && k0 + j <= q) ? __expf(v[j] - mall) : 0.f;
        v[j] = e;
        sum += e;
    }
    #pragma unroll
    for (int o = 32; o > 0; o >>= 1) sum += __shfl_down(sum, o, 64);
    if (lane == 0) red[wv] = sum;
    __syncthreads();
    const float inv = 1.f / (red[0] + red[1] + red[2] + red[3]);

    const int kceil = ((q >> 7) + 1) << 7;       // PV reads cols < kceil
    if (k0 < kceil) {
        h8 o = { (_Float16)(v[0] * inv), (_Float16)(v[1] * inv),
                 (_Float16)(v[2] * inv), (_Float16)(v[3] * inv),
                 (_Float16)(v[4] * inv), (_Float16)(v[5] * inv),
                 (_Float16)(v[6] * inv), (_Float16)(v[7] * inv) };
        *(h8*)(Prow + k0) = o;
    }
}

// V (b,s,e) fp16 -> Vt (b,e,s) fp16, 64x64 LDS tiles
__global__ __launch_bounds__(256) void transpose_v_kernel(const _Float16* __restrict__ V,
                                                          _Float16* __restrict__ Vt)
{
    __shared__ _Float16 tile[64][72];
    const int b = blockIdx.z;
    const int s0 = blockIdx.x * 64;
    const int e0 = blockIdx.y * 64;
    const _Float16* Vb = V + (size_t)b * 2048 * 1024;
    _Float16* Vtb = Vt + (size_t)b * 1024 * 2048;
    const int r = threadIdx.x >> 2;
    const int c = (threadIdx.x & 3) * 16;

    const _Float16* src = &Vb[(size_t)(s0 + r) * 1024 + e0 + c];
    *(uint4*)&tile[r][c]     = *(const uint4*)src;
    *(uint4*)&tile[r][c + 8] = *(const uint4*)(src + 8);
    __syncthreads();

    h8 o0, o1;
    #pragma unroll
    for (int j = 0; j < 8; j++) o0[j] = tile[c + j][r];
    #pragma unroll
    for (int j = 0; j < 8; j++) o1[j] = tile[c + 8 + j][r];
    _Float16* dst = &Vtb[(size_t)(e0 + r) * 2048 + s0 + c];
    *(h8*)dst       = o0;
    *(h8*)(dst + 8) = o1;
}

extern "C" void kernel_launch(void* const* d_in, const int* in_sizes, int n_in,
                              void* d_out, int out_size, void* d_ws, size_t ws_size,
                              hipStream_t stream) {
    const float* x  = (const float*)d_in[0];
    const float* Wq = (const float*)d_in[1];
    const float* Wk = (const float*)d_in[2];
    const float* Wv = (const float*)d_in[3];
    float* out = (float*)d_out;

    const size_t MiB = 1024 * 1024;
    char* ws = (char*)d_ws;
    _Float16* QKVh = (_Float16*)ws;                     // 48 MiB (3 slabs)
    _Float16* Vh   = QKVh + (size_t)2 * 8388608;        // V slab at +32 MiB
    float*    S    = (float*)(ws + 48 * MiB);           // 64 MiB
    _Float16* x_h  = (_Float16*)(ws + 48 * MiB);        // 16 MiB (over S)
    _Float16* Wh   = (_Float16*)(ws + 64 * MiB);        // 6 MiB  (over S)
    _Float16* P    = (_Float16*)ws;                     // 32 MiB (over Q,K)
    _Float16* Vt   = (_Float16*)(ws + 48 * MiB);        // 16 MiB (over S, AFTER softmax)

    const dim3 blk(256);

    // 0) fp32 -> fp16 conversions (one dispatch)
    cvt_all<<<dim3(5632), blk, 0, stream>>>(x, Wq, Wk, Wv, x_h, Wh);

    // 1) QKV fused: M=8192, N=3072, XCD-residue swizzle, slab-store epilogue
    gemm_nt<1, 2, false><<<dim3(1536), blk, 0, stream>>>(
        x_h, Wh, QKVh, 3072, 1024, 0, 0, 0);

    // 2) scores: balanced lower-triangle decode, 136 tiles/batch
    gemm_nt<2, 0, false><<<dim3(136, 1, 4), blk, 0, stream>>>(
        QKVh, QKVh + 8388608, S, 2048, 1024,
        (size_t)2097152, (size_t)2097152, (size_t)4194304);

    // 3) causal softmax rows -> P fp16 (over Q,K)
    softmax_causal<<<dim3(4 * 2048), blk, 0, stream>>>(S, P);

    // 4) V -> Vt (b,e,s) (over S — only safe after softmax consumed S)
    transpose_v_kernel<<<dim3(32, 16, 4), blk, 0, stream>>>(Vh, Vt);

    // 5) out = P @ Vt^T, fp32 out, K clipped at m0+128, residue swizzle
    gemm_nt<3, 0, true><<<dim3(128, 1, 4), blk, 0, stream>>>(
        P, Vt, out, 1024, 2048,
        (size_t)4194304, (size_t)2097152, (size_t)2097152);
}

// Round 8
// 242.043 us; speedup vs baseline: 1.2795x; 1.0591x over previous
//
#include <hip/hip_runtime.h>

// ---------------------------------------------------------------------------
// SelfAttention: B=4, S=2048, D=1024, fp32 in/out, causal, no 1/sqrt(d).
// fp16 MFMA (16x16x32), fp32 accumulate, fp32 softmax.
// R8 = R7 + (a) XOR-swizzled LDS layout: global_load_lds pins LDS addr to
// lane*16, so we permute the GLOBAL source chunk per lane (gsrc=(l&3)^((l>>3)&3))
// and read fragments at sg=qd^((la>>1)&3) — spreads each 16-lane phase across
// all 8 bank-groups (R7 had ~8-way conflicts, 6.29M conflict cycles on QKV);
// (b) QKV epilogue writes the V slab directly transposed (b,e,s) -> transpose
// kernel deleted, Vt lives at [32,48) MiB (no S-overlay hazard).
//
// ws layout (MiB):
//   [0,32)    Q,K fp16 slabs; later P fp16 overlays (after scores read Q,K)
//   [32,48)   Vt fp16 (b,e,s) — written by QKV epilogue
//   [48,112)  S fp32 (4x2048x2048)
//   [48,64)   x_h fp16      (over S; dead before S written)
//   [64,70)   Wh  fp16 [3072,1024] (over S; dead before S written)
// ---------------------------------------------------------------------------

typedef _Float16 h8 __attribute__((ext_vector_type(8)));
typedef _Float16 h4 __attribute__((ext_vector_type(4)));
typedef float f32x4 __attribute__((ext_vector_type(4)));

#define BM 128
#define BN 128

__device__ __forceinline__ void gl_lds16(const _Float16* g, _Float16* l) {
    __builtin_amdgcn_global_load_lds(
        (const __attribute__((address_space(1))) void*)g,
        (__attribute__((address_space(3))) void*)l, 16, 0, 0);
}

// NT GEMM: C[m][n] = sum_k A[m][k]*B[n][k]; A,B fp16 row-major, stride K.
// SWZ: 1 = QKV residue (grid.x=1536), 2 = scores balanced triangle (136),
//      3 = PV residue (128). OM: 0 = fp32 C (ldc=N, +z*sCz), 2 = QKV slab
//      store (Q,K row-major; V transposed to (b,e,s)). KLIM: clip K at m0+BM.
template<int SWZ, int OM, bool KLIM>
__global__ __launch_bounds__(256) void gemm_nt(
    const _Float16* __restrict__ A, const _Float16* __restrict__ B,
    void* __restrict__ Cp, int N, int K,
    size_t sAz, size_t sBz, size_t sCz)
{
    __shared__ __align__(16) char smem[32768];
    _Float16* As = (_Float16*)smem;              // 2 x 4096 halves (k-stages)
    _Float16* Bs = (_Float16*)(smem + 16384);    // 2 x 4096 halves

    int bx, by;
    if (SWZ == 1) {
        const int r = blockIdx.x & 7, q2 = blockIdx.x >> 3;
        bx = q2 >> 3;
        by = ((q2 & 7) << 3) | r;
    } else if (SWZ == 2) {
        const int r = blockIdx.x & 7, g = blockIdx.x >> 3;   // g in 0..16
        if (g <= r) { by = r;      bx = g; }
        else        { by = 15 - r; bx = g - (r + 1); }
    } else {                                      // SWZ == 3
        const int r = blockIdx.x & 7, g = blockIdx.x >> 3;   // g in 0..15
        by = (g & 1) ? (15 - r) : r;
        bx = g >> 1;
    }

    const int tid  = threadIdx.x;
    const int lane = tid & 63;
    const int wv   = tid >> 6;
    const int m0 = by * BM, n0 = bx * BN;
    const size_t z = blockIdx.z;

    // staging (per 8KB stage): 8 chunks of 1KB; wave wv stages chunks {wv,wv+4};
    // lane l -> row 16c+(l>>2); XOR-swizzled source group gsrc=(l&3)^((l>>3)&3)
    // (LDS dst is forced to c*1KB + l*16B, so the swizzle lives in the global
    // source pick; reads undo it via sg = qd ^ ((la>>1)&3)).
    const int lr = lane >> 2;
    const int lc = ((lane & 3) ^ ((lane >> 3) & 3)) * 8;
    const _Float16* pA0 = A + z * sAz + (size_t)(m0 + wv * 16 + lr) * K + lc;
    const _Float16* pA1 = pA0 + (size_t)64 * K;
    const _Float16* pB0 = B + z * sBz + (size_t)(n0 + wv * 16 + lr) * K + lc;
    const _Float16* pB1 = pB0 + (size_t)64 * K;
    _Float16* lA0 = As + wv * 512;
    _Float16* lA1 = As + (wv + 4) * 512;
    _Float16* lB0 = Bs + wv * 512;
    _Float16* lB1 = Bs + (wv + 4) * 512;

    // MFMA geometry: 4 waves 2x2, each wave 64x64 = 4x4 frags of 16x16x32
    const int la = lane & 15;
    const int qd = lane >> 4;
    const int wm = (wv >> 1) * 64;
    const int wn = (wv & 1) * 64;
    const int sg = (qd ^ ((la >> 1) & 3)) * 8;   // swizzled k-group offset

    f32x4 acc[4][4];
    #pragma unroll
    for (int i = 0; i < 4; i++)
        #pragma unroll
        for (int j = 0; j < 4; j++)
            acc[i][j] = (f32x4){0.f, 0.f, 0.f, 0.f};

    const int kEnd = KLIM ? (m0 + BM) : K;

    for (int k0 = 0; k0 < kEnd; k0 += 64) {
        gl_lds16(pA0,      lA0);
        gl_lds16(pA1,      lA1);
        gl_lds16(pB0,      lB0);
        gl_lds16(pB1,      lB1);
        gl_lds16(pA0 + 32, lA0 + 4096);
        gl_lds16(pA1 + 32, lA1 + 4096);
        gl_lds16(pB0 + 32, lB0 + 4096);
        gl_lds16(pB1 + 32, lB1 + 4096);
        pA0 += 64; pA1 += 64; pB0 += 64; pB1 += 64;
        __syncthreads();

        #pragma unroll
        for (int s = 0; s < 2; s++) {
            h8 af[4], bf[4];
            #pragma unroll
            for (int i = 0; i < 4; i++)
                af[i] = *(const h8*)&As[s * 4096 + (wm + i * 16 + la) * 32 + sg];
            #pragma unroll
            for (int i = 0; i < 4; i++)
                bf[i] = *(const h8*)&Bs[s * 4096 + (wn + i * 16 + la) * 32 + sg];
            #pragma unroll
            for (int i = 0; i < 4; i++)
                #pragma unroll
                for (int j = 0; j < 4; j++)
                    acc[i][j] = __builtin_amdgcn_mfma_f32_16x16x32_f16(af[i], bf[j], acc[i][j], 0, 0, 0);
        }
        __syncthreads();
    }

    // epilogue: D layout col=lane&15, row=qd*4+reg
    if (OM == 2) {
        _Float16* C = (_Float16*)Cp;
        if (n0 < 2048) {
            // Q/K slabs, row-major [s][e], within-slab ld 1024
            #pragma unroll
            for (int i = 0; i < 4; i++)
                #pragma unroll
                for (int j = 0; j < 4; j++) {
                    const int col  = n0 + wn + j * 16 + la;
                    const size_t base = (size_t)(col >> 10) * 8388608 + (col & 1023);
                    #pragma unroll
                    for (int rr = 0; rr < 4; rr++)
                        C[base + (size_t)(m0 + wm + i * 16 + qd * 4 + rr) * 1024] =
                            (_Float16)acc[i][j][rr];
                }
        } else {
            // V slab stored transposed: Vt (b, e, s) at slab 2; rr -> s contiguous
            _Float16* Vt = C + (size_t)2 * 8388608;
            #pragma unroll
            for (int i = 0; i < 4; i++) {
                const int m  = m0 + wm + i * 16 + qd * 4;
                const int b  = m >> 11;
                const int sl = m & 2047;
                _Float16* Vb = Vt + (size_t)b * 2097152 + sl;
                #pragma unroll
                for (int j = 0; j < 4; j++) {
                    const int e = n0 - 2048 + wn + j * 16 + la;
                    h4 vv = { (_Float16)acc[i][j][0], (_Float16)acc[i][j][1],
                              (_Float16)acc[i][j][2], (_Float16)acc[i][j][3] };
                    *(h4*)(Vb + (size_t)e * 2048) = vv;
                }
            }
        }
    } else {
        float* C = (float*)Cp + z * sCz;
        #pragma unroll
        for (int i = 0; i < 4; i++)
            #pragma unroll
            for (int j = 0; j < 4; j++)
                #pragma unroll
                for (int rr = 0; rr < 4; rr++)
                    C[(size_t)(m0 + wm + i * 16 + qd * 4 + rr) * N + (n0 + wn + j * 16 + la)] =
                        acc[i][j][rr];
    }
}

// fused fp32->fp16: blocks [0,4096) convert x (8M), [4096,5632) convert W (3x1M)
__global__ __launch_bounds__(256) void cvt_all(
    const float* __restrict__ x, const float* __restrict__ Wq,
    const float* __restrict__ Wk, const float* __restrict__ Wv,
    _Float16* __restrict__ x_h, _Float16* __restrict__ Wh)
{
    const int bid = blockIdx.x;
    const float* src; _Float16* dst; size_t off;
    if (bid < 4096) {
        src = x; dst = x_h; off = (size_t)bid * 2048;
    } else {
        const int b2 = bid - 4096;
        const int w = b2 >> 9;
        src = (w == 0) ? Wq : ((w == 1) ? Wk : Wv);
        dst = Wh + (size_t)w * 1048576;
        off = (size_t)(b2 & 511) * 2048;
    }
    const size_t i = off + (size_t)threadIdx.x * 8;
    float4 a = *(const float4*)(src + i);
    float4 b = *(const float4*)(src + i + 4);
    h8 o = { (_Float16)a.x, (_Float16)a.y, (_Float16)a.z, (_Float16)a.w,
             (_Float16)b.x, (_Float16)b.y, (_Float16)b.z, (_Float16)b.w };
    *(h8*)(dst + i) = o;
}

// causal row softmax: S fp32 -> P fp16. Thread t owns cols 8t..8t+7.
// Reads only k<=q; writes only k < 128-ceil(q+1) (PV's KLIM never reads more).
__global__ __launch_bounds__(256) void softmax_causal(const float* __restrict__ S,
                                                      _Float16* __restrict__ P)
{
    const int idx = blockIdx.x;          // 0..8191
    const int q = idx & 2047;
    const float* Srow = S + (size_t)idx * 2048;
    _Float16* Prow = P + (size_t)idx * 2048;
    const int t = threadIdx.x;
    const int k0 = t * 8;
    const int lane = t & 63, wv = t >> 6;
    __shared__ float red[4];

    float v[8];
    const bool any = (k0 <= q);
    if (any) {
        float4 a = *(const float4*)(Srow + k0);
        float4 b = *(const float4*)(Srow + k0 + 4);
        v[0] = a.x; v[1] = a.y; v[2] = a.z; v[3] = a.w;
        v[4] = b.x; v[5] = b.y; v[6] = b.z; v[7] = b.w;
    }
    float mx = -3.4e38f;
    #pragma unroll
    for (int j = 0; j < 8; j++)
        if (any && k0 + j <= q) mx = fmaxf(mx, v[j]);
    #pragma unroll
    for (int o = 32; o > 0; o >>= 1) mx = fmaxf(mx, __shfl_down(mx, o, 64));
    if (lane == 0) red[wv] = mx;
    __syncthreads();
    const float mall = fmaxf(fmaxf(red[0], red[1]), fmaxf(red[2], red[3]));
    __syncthreads();

    float sum = 0.f;
    #pragma unroll
    for (int j = 0; j < 8; j++) {
        float e = (any && k0 + j <= q) ? __expf(v[j] - mall) : 0.f;
        v[j] = e;
        sum += e;
    }
    #pragma unroll
    for (int o = 32; o > 0; o >>= 1) sum += __shfl_down(sum, o, 64);
    if (lane == 0) red[wv] = sum;
    __syncthreads();
    const float inv = 1.f / (red[0] + red[1] + red[2] + red[3]);

    const int kceil = ((q >> 7) + 1) << 7;       // PV reads cols < kceil
    if (k0 < kceil) {
        h8 o = { (_Float16)(v[0] * inv), (_Float16)(v[1] * inv),
                 (_Float16)(v[2] * inv), (_Float16)(v[3] * inv),
                 (_Float16)(v[4] * inv), (_Float16)(v[5] * inv),
                 (_Float16)(v[6] * inv), (_Float16)(v[7] * inv) };
        *(h8*)(Prow + k0) = o;
    }
}

extern "C" void kernel_launch(void* const* d_in, const int* in_sizes, int n_in,
                              void* d_out, int out_size, void* d_ws, size_t ws_size,
                              hipStream_t stream) {
    const float* x  = (const float*)d_in[0];
    const float* Wq = (const float*)d_in[1];
    const float* Wk = (const float*)d_in[2];
    const float* Wv = (const float*)d_in[3];
    float* out = (float*)d_out;

    const size_t MiB = 1024 * 1024;
    char* ws = (char*)d_ws;
    _Float16* QKVh = (_Float16*)ws;                     // Q,K slabs + Vt at slab 2
    _Float16* Vt   = QKVh + (size_t)2 * 8388608;        // [32,48) MiB, (b,e,s)
    float*    S    = (float*)(ws + 48 * MiB);           // 64 MiB
    _Float16* x_h  = (_Float16*)(ws + 48 * MiB);        // 16 MiB (over S)
    _Float16* Wh   = (_Float16*)(ws + 64 * MiB);        // 6 MiB  (over S)
    _Float16* P    = (_Float16*)ws;                     // 32 MiB (over Q,K)

    const dim3 blk(256);

    // 0) fp32 -> fp16 conversions (one dispatch)
    cvt_all<<<dim3(5632), blk, 0, stream>>>(x, Wq, Wk, Wv, x_h, Wh);

    // 1) QKV fused: M=8192, N=3072; Q,K row-major slabs, V written as Vt(b,e,s)
    gemm_nt<1, 2, false><<<dim3(1536), blk, 0, stream>>>(
        x_h, Wh, QKVh, 3072, 1024, 0, 0, 0);

    // 2) scores: balanced lower-triangle decode, 136 tiles/batch
    gemm_nt<2, 0, false><<<dim3(136, 1, 4), blk, 0, stream>>>(
        QKVh, QKVh + 8388608, S, 2048, 1024,
        (size_t)2097152, (size_t)2097152, (size_t)4194304);

    // 3) causal softmax rows -> P fp16 (over Q,K)
    softmax_causal<<<dim3(4 * 2048), blk, 0, stream>>>(S, P);

    // 4) out = P @ Vt^T, fp32 out, K clipped at m0+128, residue swizzle
    gemm_nt<3, 0, true><<<dim3(128, 1, 4), blk, 0, stream>>>(
        P, Vt, out, 1024, 2048,
        (size_t)4194304, (size_t)2097152, (size_t)2097152);
}